// Round 4
// baseline (1339.678 us; speedup 1.0000x reference)
//
#include <hip/hip_runtime.h>
#include <math.h>

#define B_    2
#define S_    2048
#define M_TOT 4096
#define DIM_  2048
#define NH_   16
#define QL_   1536
#define KVL_  512
#define QKN_  128
#define QKR_  64
#define VH_   128
#define QKH_  192
#define QSTR  3072      // NH_*QKH_
#define QP_STR 584      // padded LDS row stride for resident Q (576+8)

typedef short s16x8 __attribute__((ext_vector_type(8)));
typedef float f32x4 __attribute__((ext_vector_type(4)));
typedef unsigned short u16;
#define AS1 __attribute__((address_space(1)))
#define AS3 __attribute__((address_space(3)))

__device__ inline u16 f2bf(float f) {
    unsigned u = __float_as_uint(f);
    unsigned r = u + 0x7FFFu + ((u >> 16) & 1u);   // round-to-nearest-even
    return (u16)(r >> 16);
}
__device__ inline float bf2f(u16 h) { return __uint_as_float(((unsigned)h) << 16); }

__device__ __forceinline__ void ld_lds16(const u16* g, u16* l) {
    __builtin_amdgcn_global_load_lds((const AS1 unsigned*)g, (AS3 unsigned*)l, 16, 0, 0);
}
// Raw barriers with explicit publishes. NEVER __syncthreads() in the hot loop:
// its implicit "s_waitcnt vmcnt(0) lgkmcnt(0); s_barrier" drains the
// global_load_lds queue at phase TOP, serializing every phase on load latency.
__device__ __forceinline__ void bar_vm() {      // publish this wave's DMA loads
    asm volatile("s_waitcnt vmcnt(0)" ::: "memory");
    __builtin_amdgcn_s_barrier();
}
__device__ __forceinline__ void bar_lgkm() {    // publish this wave's ds_writes
    asm volatile("s_waitcnt lgkmcnt(0)" ::: "memory");
    __builtin_amdgcn_s_barrier();
}
__device__ __forceinline__ void bar_all() {
    asm volatile("s_waitcnt vmcnt(0) lgkmcnt(0)" ::: "memory");
    __builtin_amdgcn_s_barrier();
}

// ---------------------------------------------------------------------------
// m97-pattern bf16 MFMA GEMM (known good since round 2).
// ---------------------------------------------------------------------------
__global__ __launch_bounds__(256)
void gemm_bf16(const u16* __restrict__ A, const u16* __restrict__ Bm,
               const float* __restrict__ bias, void* __restrict__ Cv,
               int M, int N, int K, int ldA, int ldB, int ldC,
               long long sAz, long long sBz, long long sCz,
               float alpha, int outF32)
{
    __shared__ u16 As[128 * 32];
    __shared__ u16 Bs[128 * 32];
    const int tid = threadIdx.x;
    const int w = tid >> 6, l = tid & 63;
    const int m0 = blockIdx.y * 128, n0 = blockIdx.x * 128;
    const int z = blockIdx.z;
    const u16* Az = A + (size_t)z * sAz;
    const u16* Bz = Bm + (size_t)z * sBz;

    const int rin = l >> 2;
    const int cel = (l & 3) * 8;
    const int lane15 = l & 15, quad = l >> 4;
    const int wm = w & 1, wn = w >> 1;

    f32x4 acc[4][4] = {};

    for (int k0 = 0; k0 < K; k0 += 32) {
        __syncthreads();
        #pragma unroll
        for (int c = 0; c < 2; ++c) {
            const int chunk = w * 2 + c;
            const int rowA = m0 + chunk * 16 + rin;
            const u16* ga = Az + (size_t)rowA * ldA + k0 + cel;
            u16* la = &As[chunk * 512 + rin * 32 + cel];
            __builtin_amdgcn_global_load_lds((const AS1 unsigned*)ga, (AS3 unsigned*)la, 16, 0, 0);
            int rowB = n0 + chunk * 16 + rin;
            if (rowB > N - 1) rowB = N - 1;
            const u16* gb = Bz + (size_t)rowB * ldB + k0 + cel;
            u16* lb = &Bs[chunk * 512 + rin * 32 + cel];
            __builtin_amdgcn_global_load_lds((const AS1 unsigned*)gb, (AS3 unsigned*)lb, 16, 0, 0);
        }
        __syncthreads();
        s16x8 af[4], bf[4];
        #pragma unroll
        for (int i = 0; i < 4; ++i)
            af[i] = *(const s16x8*)&As[(wm * 64 + i * 16 + lane15) * 32 + quad * 8];
        #pragma unroll
        for (int i = 0; i < 4; ++i)
            bf[i] = *(const s16x8*)&Bs[(wn * 64 + i * 16 + lane15) * 32 + quad * 8];
        #pragma unroll
        for (int mi = 0; mi < 4; ++mi)
            #pragma unroll
            for (int ni = 0; ni < 4; ++ni)
                acc[mi][ni] = __builtin_amdgcn_mfma_f32_16x16x32_bf16(af[mi], bf[ni], acc[mi][ni], 0, 0, 0);
    }

    const int cmb = m0 + wm * 64, cnb = n0 + wn * 64;
    if (outF32) {
        float* C = (float*)Cv + (size_t)z * sCz;
        #pragma unroll
        for (int mi = 0; mi < 4; ++mi)
            #pragma unroll
            for (int ni = 0; ni < 4; ++ni) {
                const int nn = cnb + ni * 16 + lane15;
                if (nn < N) {
                    const float bv = bias ? bias[nn] : 0.f;
                    #pragma unroll
                    for (int r = 0; r < 4; ++r) {
                        const int mm = cmb + mi * 16 + quad * 4 + r;
                        C[(size_t)mm * ldC + nn] = acc[mi][ni][r] * alpha + bv;
                    }
                }
            }
    } else {
        u16* C = (u16*)Cv + (size_t)z * sCz;
        #pragma unroll
        for (int mi = 0; mi < 4; ++mi)
            #pragma unroll
            for (int ni = 0; ni < 4; ++ni) {
                const int nn = cnb + ni * 16 + lane15;
                if (nn < N) {
                    const float bv = bias ? bias[nn] : 0.f;
                    #pragma unroll
                    for (int r = 0; r < 4; ++r) {
                        const int mm = cmb + mi * 16 + quad * 4 + r;
                        C[(size_t)mm * ldC + nn] = f2bf(acc[mi][ni][r] * alpha + bv);
                    }
                }
            }
    }
}

// ---------------------------------------------------------------------------
// Flash v6: 2 blocks/CU. v5 (1 block of 512 thr, 160KB LDS) was lockstep-
// serialized: busiest pipe only ~30% busy (MFMA 5.3K + VALU 6.1K + LDS 5-10K
// cyc/k-tile vs 28K wall) because softmax/barriers/DMA residue expose with a
// single resident block. v6: 256 thr / 4 waves / 32 q-rows; K in 64-dim
// chunks (9 score phases), V in (tc, c-half) 16KB chunks (8 PV phases).
// LDS = 37376(Q) + 32768(K/V dbuf) + 8704(P) + 1280(misc) = 80128 <= 81920
// -> 2 independent blocks/CU; block A's softmax overlaps block B's MFMA.
// Per-wave fragment geometry and the source-permute XOR swizzle (sx8/qx8)
// are IDENTICAL to v5 (sub-block layouts [128 rows][32 dims] unchanged).
// Also: klen masked-tile skip (last k-tile avg 37% fully-masked at 32-row
// tiles; wave-uniform skip of dead score slices / PV chunks + their V
// staging); T13 defer-max (skip O-rescale when max growth <= 8, wave-uniform
// __all); exp2-domain softmax (scale*log2e folded -> bare v_exp_f32).
// Buffer parity: 17 phases/k-tile (odd) -> runtime parity pb toggles per
// tile; buf(phase) = (phase+pb)&1, stage into buf^1, bar_vm after (drain
// sits after compute -> latency hidden; loads in flight across barriers).
// All hot-loop barrier guards are block-uniform (klen from qs,kt only) ->
// no divergent-barrier deadlock. Round-3 bench failure was container infra
// (no compile/pytest error, acquire flakiness in round-2 timing); v6 audit
// found no defect -> resubmitted unchanged for a clean measurement.
// ---------------------------------------------------------------------------
__global__ __launch_bounds__(256)
void mla_flash(u16* __restrict__ Qp, const u16* __restrict__ Kcat,
               const u16* __restrict__ KVT)
{
    __shared__ u16 sQ[32 * QP_STR];          // 37376 B
    __shared__ u16 sKV[2][8192];             // 32768 B (two 16KB chunks)
    __shared__ u16 sP[32 * 136];             // 8704 B
    __shared__ float sRm[32 * 4];            // per-row max partials (4 k-slices)
    __shared__ float sRs[32 * 4];            // per-row sum partials
    __shared__ float sM[32], sL[32];

    const int tid = threadIdx.x;
    const int w = tid >> 6, l = tid & 63;    // w: score k-slice / PV c-sub-slice
    const int lane15 = l & 15, quad = l >> 4;

    // --- XCD-aware decode (bijective over 2048): b pinned per XCD half ---
    const int flat = blockIdx.x;
    const int xcd  = flat & 7;
    const int slot = flat >> 3;              // 0..255
    const int b    = xcd >> 2;
    const int h    = (xcd & 3) * 4 + (slot & 3);
    const int qt   = 63 - (slot >> 2);       // heavy tiles first
    const int qs   = qt * 32;

    u16* Qrow = Qp + ((size_t)h * M_TOT + b * S_ + qs) * 576;
    const float scale2 = 0.10411758f;        // (1/sqrt(192)) * log2(e)
    const u16* Kb = Kcat + (size_t)b * S_ * 576;
    const u16* Vb = KVT + (size_t)b * 512 * S_;

    const int seg8 = (tid & 3) * 8;          // linear LDS dest segment
    const int sx8  = (((tid & 3) ^ ((tid >> 3) & 3)) * 8);   // permuted SRC segment
    const int qx8  = ((quad ^ ((lane15 >> 1) & 3)) * 8);     // permuted READ segment
    const int ktiles = (qs + 159) >> 7;      // keys needed <= qs+31

    // K chunk j (dims j*64..+64): two [128 keys][32 dims] sub-blocks, 2 passes
    auto stageK = [&](int kt, int j, int buf) {
        #pragma unroll
        for (int kk = 0; kk < 2; ++kk)
            #pragma unroll
            for (int ps = 0; ps < 2; ++ps) {
                const int key = (tid >> 2) + ps * 64;
                const u16* g = Kb + (size_t)(kt + key) * 576 + j * 64 + kk * 32 + sx8;
                ld_lds16(g, &sKV[buf][kk * 4096 + key * 32 + seg8]);
            }
    };
    // V chunk (tc, hf): c in [hf*256,+256) as two [128][32] sub-blocks
    auto stageV = [&](int kt, int tc, int hf, int buf) {
        #pragma unroll
        for (int jj = 0; jj < 2; ++jj)
            #pragma unroll
            for (int ps = 0; ps < 2; ++ps) {
                const int rl = (tid >> 2) + ps * 64;
                const int c  = hf * 256 + jj * 128 + rl;
                const u16* g = Vb + (size_t)c * S_ + kt + tc * 32 + sx8;
                ld_lds16(g, &sKV[buf][jj * 4096 + rl * 32 + seg8]);
            }
    };

    // ---- prologue: issue K chunk 0 first, hide under Q fill ----
    stageK(0, 0, 0);
    {
        const int r = tid >> 3, c0 = (tid & 7) * 8;   // 32 rows x 576
        #pragma unroll
        for (int jj = 0; jj < 9; ++jj) {
            const int c = c0 + jj * 64;
            *(s16x8*)&sQ[r * QP_STR + c] = *(const s16x8*)&Qrow[(size_t)r * 576 + c];
        }
    }
    if (tid < 32) { sM[tid] = -1e30f; sL[tid] = 0.f; }
    bar_all();

    f32x4 Oacc[2][8] = {};                   // rows mi*16+..., cols hf*256+w*64+ci*16+...
    float mn_[2][4], al_[2][4];
    int pb = 0;                              // per-tile buffer parity

    for (int kt0 = 0; kt0 < ktiles; ++kt0) {
        const int kt = kt0 << 7;
        const int klen = min(128, qs + 32 - kt);   // valid keys this tile
        f32x4 Sacc[2][2] = {};

        // ---- score: S(32x128) = Q . K^T, 9 phases of 64 dims ----
        #pragma unroll
        for (int j = 0; j < 9; ++j) {
            const int cur = (j + pb) & 1;
            if (j < 8) stageK(kt, j + 1, cur ^ 1);
            else       stageV(kt, 0, 0, cur ^ 1);  // V(0,0) in flight across softmax
            if (w * 32 < klen) {
                __builtin_amdgcn_s_setprio(1);
                #pragma unroll
                for (int kk = 0; kk < 2; ++kk) {
                    s16x8 af[2], bf[2];
                    #pragma unroll
                    for (int mi = 0; mi < 2; ++mi)
                        af[mi] = *(const s16x8*)&sQ[(mi * 16 + lane15) * QP_STR + j * 64 + kk * 32 + quad * 8];
                    #pragma unroll
                    for (int ni = 0; ni < 2; ++ni)
                        bf[ni] = *(const s16x8*)&sKV[cur][kk * 4096 + (w * 32 + ni * 16 + lane15) * 32 + qx8];
                    #pragma unroll
                    for (int mi = 0; mi < 2; ++mi)
                        #pragma unroll
                        for (int ni = 0; ni < 2; ++ni)
                            Sacc[mi][ni] = __builtin_amdgcn_mfma_f32_16x16x32_bf16(af[mi], bf[ni], Sacc[mi][ni], 0, 0, 0);
                }
                __builtin_amdgcn_s_setprio(0);
            }
            if (j < 8) bar_vm();             // publish K(j+1); j=8 needs no barrier
        }

        // ---- softmax part 1: scale + causal mask + per-slice row max ----
        #pragma unroll
        for (int mi = 0; mi < 2; ++mi)
            #pragma unroll
            for (int r = 0; r < 4; ++r) {
                const int rowl = mi * 16 + quad * 4 + r;
                const int rowg = qs + rowl;
                float mx = -1e30f;
                #pragma unroll
                for (int ni = 0; ni < 2; ++ni) {
                    const int colg = kt + w * 32 + ni * 16 + lane15;
                    float v = Sacc[mi][ni][r] * scale2;
                    v = (colg <= rowg) ? v : -1e30f;
                    Sacc[mi][ni][r] = v;
                    mx = fmaxf(mx, v);
                }
                #pragma unroll
                for (int sh = 1; sh < 16; sh <<= 1) mx = fmaxf(mx, __shfl_xor(mx, sh));
                if (lane15 == 0) sRm[rowl * 4 + w] = mx;
            }
        bar_lgkm();                          // (A): sRm visible

        // ---- part 2: m/alpha (T13 defer-max), P, row sums ----
        float dmax = 0.f;
        #pragma unroll
        for (int mi = 0; mi < 2; ++mi)
            #pragma unroll
            for (int r = 0; r < 4; ++r) {
                const int rowl = mi * 16 + quad * 4 + r;
                const f32x4 pm = *(const f32x4*)&sRm[rowl * 4];
                const float m_old = sM[rowl];
                const float mnc = fmaxf(fmaxf(pm[0], pm[1]), fmaxf(pm[2], pm[3]));
                dmax = fmaxf(dmax, mnc - m_old);
                mn_[mi][r] = mnc;            // candidate
                al_[mi][r] = m_old;          // stash m_old
            }
        const bool rescale = !__all(dmax <= 8.f);   // wave-uniform, same all waves
        #pragma unroll
        for (int mi = 0; mi < 2; ++mi)
            #pragma unroll
            for (int r = 0; r < 4; ++r) {
                const float m_old = al_[mi][r];
                if (rescale) {
                    const float mn = fmaxf(mn_[mi][r], m_old);
                    al_[mi][r] = exp2f(m_old - mn);
                    mn_[mi][r] = mn;
                } else {
                    mn_[mi][r] = m_old;
                    al_[mi][r] = 1.f;
                }
            }
        if (rescale) {
            #pragma unroll
            for (int mi = 0; mi < 2; ++mi)
                #pragma unroll
                for (int ci = 0; ci < 8; ++ci)
                    #pragma unroll
                    for (int r = 0; r < 4; ++r)
                        Oacc[mi][ci][r] *= al_[mi][r];
        }
        #pragma unroll
        for (int mi = 0; mi < 2; ++mi)
            #pragma unroll
            for (int r = 0; r < 4; ++r) {
                const int rowl = mi * 16 + quad * 4 + r;
                const float mn = mn_[mi][r];
                float sum = 0.f;
                #pragma unroll
                for (int ni = 0; ni < 2; ++ni) {
                    const float p = exp2f(Sacc[mi][ni][r] - mn);
                    sP[rowl * 136 + w * 32 + ni * 16 + lane15] = f2bf(p);
                    sum += p;
                }
                #pragma unroll
                for (int sh = 1; sh < 16; sh <<= 1) sum += __shfl_xor(sum, sh);
                if (lane15 == 0) sRs[rowl * 4 + w] = sum;
            }
        bar_all();                           // (C): sP + sRs visible, V(0,0) arrived

        // ---- part 3: designated lanes update per-row m/l ----
        if (w == 0 && lane15 == 0) {
            #pragma unroll
            for (int mi = 0; mi < 2; ++mi)
                #pragma unroll
                for (int r = 0; r < 4; ++r) {
                    const int rowl = mi * 16 + quad * 4 + r;
                    const f32x4 ps = *(const f32x4*)&sRs[rowl * 4];
                    sL[rowl] = sL[rowl] * al_[mi][r] + (ps[0] + ps[1] + ps[2] + ps[3]);
                    sM[rowl] = mn_[mi][r];
                }
        }

        // ---- PV: O(32x512) += P(32x128) . KV(128x512); phases (tc, c-half) ----
        #pragma unroll
        for (int tc = 0; tc < 4; ++tc) {
            const bool live = (tc * 32 < klen);
            s16x8 pf[2];
            if (live) {
                #pragma unroll
                for (int mi = 0; mi < 2; ++mi)
                    pf[mi] = *(const s16x8*)&sP[(mi * 16 + lane15) * 136 + tc * 32 + quad * 8];
            }
            #pragma unroll
            for (int hf = 0; hf < 2; ++hf) {
                const int ph  = 9 + tc * 2 + hf;
                const int cur = (ph + pb) & 1;
                const bool last = (tc == 3 && hf == 1);
                if (last) {
                    if (kt0 + 1 < ktiles) stageK(kt + 128, 0, cur ^ 1);
                } else {
                    const int ntc = tc + hf;         // next chunk (tc,1) or (tc+1,0)
                    const int nhf = hf ^ 1;
                    if (ntc * 32 < klen) stageV(kt, ntc, nhf, cur ^ 1);
                }
                if (live) {
                    s16x8 vf[4];
                    #pragma unroll
                    for (int ci = 0; ci < 4; ++ci) {
                        const int rl = w * 64 + ci * 16 + lane15;   // 0..255 in half
                        vf[ci] = *(const s16x8*)&sKV[cur][(rl >> 7) * 4096 + (rl & 127) * 32 + qx8];
                    }
                    __builtin_amdgcn_s_setprio(1);
                    #pragma unroll
                    for (int mi = 0; mi < 2; ++mi)
                        #pragma unroll
                        for (int ci = 0; ci < 4; ++ci)
                            Oacc[mi][hf * 4 + ci] = __builtin_amdgcn_mfma_f32_16x16x32_bf16(pf[mi], vf[ci], Oacc[mi][hf * 4 + ci], 0, 0, 0);
                    __builtin_amdgcn_s_setprio(0);
                }
                if (live || last) bar_vm();  // dead middle phases: no barrier needed
            }
        }
        pb ^= 1;
    }

    // ---- epilogue: O/l -> bf16, overwrite Qpack[..., 0:512] ----
    bar_lgkm();
    #pragma unroll
    for (int mi = 0; mi < 2; ++mi)
        #pragma unroll
        for (int r = 0; r < 4; ++r) {
            const int rowl = mi * 16 + quad * 4 + r;
            const float inv = 1.f / sL[rowl];
            #pragma unroll
            for (int hf = 0; hf < 2; ++hf)
                #pragma unroll
                for (int ci = 0; ci < 4; ++ci)
                    Qrow[(size_t)rowl * 576 + hf * 256 + w * 64 + ci * 16 + lane15] =
                        f2bf(Oacc[mi][hf * 4 + ci][r] * inv);
        }
}

// ---------------------------------------------------------------------------
__global__ __launch_bounds__(256)
void cast_f32_bf16(const float* __restrict__ src, u16* __restrict__ dst, int n)
{
    for (int i = blockIdx.x * 256 + threadIdx.x; i < n; i += gridDim.x * 256)
        dst[i] = f2bf(src[i]);
}

__global__ __launch_bounds__(256)
void prep_wbnT(const float* __restrict__ wkvb, u16* __restrict__ dst)
{
    int i = blockIdx.x * 256 + threadIdx.x;
    int h = i >> 16, rem = i & 65535, c = rem >> 7, d = rem & 127;
    dst[i] = f2bf(wkvb[(size_t)(h * 256 + d) * 512 + c]);
}

__global__ __launch_bounds__(256)
void prep_wbv(const float* __restrict__ wkvb, u16* __restrict__ dst)
{
    int i = blockIdx.x * 256 + threadIdx.x;
    int h = i >> 16, rem = i & 65535;
    dst[i] = f2bf(wkvb[(size_t)h * 131072 + 65536 + rem]);
}

__global__ __launch_bounds__(256)
void rmsnorm_bf16(u16* __restrict__ X, const float* __restrict__ w, int D)
{
    const int m = blockIdx.x;
    u16* x = X + (size_t)m * D;
    float ss = 0.f;
    for (int k = threadIdx.x; k < D; k += 256) { float v = bf2f(x[k]); ss += v * v; }
    __shared__ float red[256];
    red[threadIdx.x] = ss; __syncthreads();
    for (int s = 128; s > 0; s >>= 1) {
        if (threadIdx.x < s) red[threadIdx.x] += red[threadIdx.x + s];
        __syncthreads();
    }
    const float sc = rsqrtf(red[0] / (float)D + 1e-6f);
    for (int k = threadIdx.x; k < D; k += 256) x[k] = f2bf(bf2f(x[k]) * sc * w[k]);
}

// q (bf16, rows QSTR) -> rotate q_pe, write to Qpack[h][m][512:576]
__global__ __launch_bounds__(256)
void rope_q(const u16* __restrict__ q, const float* __restrict__ freqs, u16* __restrict__ Qp)
{
    const int idx = blockIdx.x * 256 + threadIdx.x;
    const int i = idx & 31, h = (idx >> 5) & 15, m = idx >> 9;
    const int s = m & (S_ - 1);
    const float c = freqs[(s * 32 + i) * 2], sn = freqs[(s * 32 + i) * 2 + 1];
    const u16* src = q + (size_t)m * QSTR + h * QKH_ + QKN_ + 2 * i;
    const float x0 = bf2f(src[0]), x1 = bf2f(src[1]);
    u16* dst = Qp + ((size_t)h * M_TOT + m) * 576 + 512 + 2 * i;
    dst[0] = f2bf(x0 * c - x1 * sn);
    dst[1] = f2bf(x1 * c + x0 * sn);
}

__global__ __launch_bounds__(256)
void kv_norm_rope(const u16* __restrict__ kva, const float* __restrict__ w,
                  const float* __restrict__ freqs, u16* __restrict__ Kcat)
{
    const int m = blockIdx.x, s = m & (S_ - 1);
    const u16* x = kva + (size_t)m * 576;
    float ss = 0.f;
    for (int k = threadIdx.x; k < 512; k += 256) { float v = bf2f(x[k]); ss += v * v; }
    __shared__ float red[256];
    red[threadIdx.x] = ss; __syncthreads();
    for (int st = 128; st > 0; st >>= 1) {
        if (threadIdx.x < st) red[threadIdx.x] += red[threadIdx.x + st];
        __syncthreads();
    }
    const float sc = rsqrtf(red[0] / 512.f + 1e-6f);
    for (int k = threadIdx.x; k < 512; k += 256)
        Kcat[(size_t)m * 576 + k] = f2bf(bf2f(x[k]) * sc * w[k]);
    if (threadIdx.x < 32) {
        const int i = threadIdx.x;
        const float c = freqs[(s * 32 + i) * 2], sn = freqs[(s * 32 + i) * 2 + 1];
        const float x0 = bf2f(x[512 + 2 * i]), x1 = bf2f(x[512 + 2 * i + 1]);
        Kcat[(size_t)m * 576 + 512 + 2 * i]     = f2bf(x0 * c - x1 * sn);
        Kcat[(size_t)m * 576 + 512 + 2 * i + 1] = f2bf(x1 * c + x0 * sn);
    }
}

__global__ __launch_bounds__(256)
void transpose_kv(const u16* __restrict__ Kcat, u16* __restrict__ KVT)
{
    __shared__ u16 t[64][65];
    const int s0 = blockIdx.x * 64, c0 = blockIdx.y * 64, b = blockIdx.z;
    #pragma unroll
    for (int i = 0; i < 16; ++i) {
        int id = i * 256 + threadIdx.x, r = id >> 6, c = id & 63;
        t[r][c] = Kcat[(size_t)(b * S_ + s0 + r) * 576 + c0 + c];
    }
    __syncthreads();
    #pragma unroll
    for (int i = 0; i < 16; ++i) {
        int id = i * 256 + threadIdx.x, r = id >> 6, c = id & 63;
        KVT[(size_t)(b * 512 + c0 + r) * S_ + s0 + c] = t[c][r];
    }
}

// ---------------------------------------------------------------------------
extern "C" void kernel_launch(void* const* d_in, const int* in_sizes, int n_in,
                              void* d_out, int out_size, void* d_ws, size_t ws_size,
                              hipStream_t stream)
{
    (void)in_sizes; (void)n_in; (void)out_size; (void)ws_size;
    const float* x         = (const float*)d_in[0];
    const float* freqs     = (const float*)d_in[1];
    const float* wq_a_w    = (const float*)d_in[4];
    const float* wq_a_b    = (const float*)d_in[5];
    const float* q_norm_w  = (const float*)d_in[6];
    const float* wq_b_w    = (const float*)d_in[7];
    const float* wq_b_b    = (const float*)d_in[8];
    const float* wkv_a_w   = (const float*)d_in[9];
    const float* wkv_a_b   = (const float*)d_in[10];
    const float* kv_norm_w = (const float*)d_in[11];
    const float* wkv_b_w   = (const float*)d_in[12];
    const float* wo_w      = (const float*)d_in[13];
    const float* wo_b      = (const float*)d_in[14];
    float* out = (float*)d_out;

    char* W = (char*)d_ws;
    u16* x_bf  = (u16*)(W + 0);
    u16* wqa   = (u16*)(W + 16777216);
    u16* wqb   = (u16*)(W + 23068672);
    u16* wkva  = (u16*)(W + 32505856);
    u16* wobf  = (u16*)(W + 34865152);
    u16* wbnT  = (u16*)(W + 43253760);
    u16* wbv   = (u16*)(W + 45350912);
    u16* q_a   = (u16*)(W + 47448064);
    u16* q     = (u16*)(W + 60030976);
    u16* kv_a  = (u16*)(W + 85196800);
    u16* Kcat  = (u16*)(W + 89915392);
    u16* KVT   = (u16*)(W + 94633984);
    u16* Qp    = (u16*)(W + 98828288);   // Qpack[h][4096][576]: q_abs|q_pe -> attn out
    u16* outh  = (u16*)(W + 174325760);

    const dim3 blk(256);

    // --- dtype prep ---
    cast_f32_bf16<<<2048, blk, 0, stream>>>(x, x_bf, M_TOT * DIM_);
    cast_f32_bf16<<<2048, blk, 0, stream>>>(wq_a_w, wqa, QL_ * DIM_);
    cast_f32_bf16<<<2048, blk, 0, stream>>>(wq_b_w, wqb, QSTR * QL_);
    cast_f32_bf16<<<2048, blk, 0, stream>>>(wkv_a_w, wkva, 576 * DIM_);
    cast_f32_bf16<<<2048, blk, 0, stream>>>(wo_w, wobf, DIM_ * DIM_);
    prep_wbnT<<<4096, blk, 0, stream>>>(wkv_b_w, wbnT);
    prep_wbv<<<4096, blk, 0, stream>>>(wkv_b_w, wbv);

    // --- q path ---
    gemm_bf16<<<dim3(12, 32, 1), blk, 0, stream>>>(x_bf, wqa, wq_a_b, q_a,
        M_TOT, QL_, DIM_, DIM_, DIM_, QL_, 0, 0, 0, 1.f, 0);
    rmsnorm_bf16<<<M_TOT, blk, 0, stream>>>(q_a, q_norm_w, QL_);
    gemm_bf16<<<dim3(24, 32, 1), blk, 0, stream>>>(q_a, wqb, wq_b_b, q,
        M_TOT, QSTR, QL_, QL_, QL_, QSTR, 0, 0, 0, 1.f, 0);
    rope_q<<<(M_TOT * NH_ * 32) / 256, blk, 0, stream>>>(q, freqs, Qp);

    // --- kv path ---
    gemm_bf16<<<dim3(5, 32, 1), blk, 0, stream>>>(x_bf, wkva, wkv_a_b, kv_a,
        M_TOT, 576, DIM_, DIM_, DIM_, 576, 0, 0, 0, 1.f, 0);
    kv_norm_rope<<<M_TOT, blk, 0, stream>>>(kv_a, kv_norm_w, freqs, Kcat);
    transpose_kv<<<dim3(32, 8, 2), blk, 0, stream>>>(Kcat, KVT);

    // --- q absorb: Qpack[h][m][0:512] = q_nope @ wkv_b[h,:128,:] ---
    gemm_bf16<<<dim3(4, 32, 16), blk, 0, stream>>>(q, wbnT, nullptr, Qp,
        M_TOT, 512, 128, QSTR, 128, 576, QKH_, 65536, (long long)M_TOT * 576, 1.f, 0);

    // --- fused flash attention v6 (2 blocks/CU, XCD-swizzled 1D grid) ---
    mla_flash<<<dim3(2048, 1, 1), dim3(256), 0, stream>>>(Qp, Kcat, KVT);

    // --- V projection: outh[m][h*128+d] = O[h][m][:] . wbv[h][d][:] ---
    gemm_bf16<<<dim3(1, 32, 16), blk, 0, stream>>>(Qp, wbv, nullptr, outh,
        M_TOT, VH_, 512, 576, 512, DIM_, (long long)M_TOT * 576, 65536, VH_, 1.f, 0);

    // --- output projection (fp32 out) ---
    gemm_bf16<<<dim3(16, 32, 1), blk, 0, stream>>>(outh, wobf, wo_b, out,
        M_TOT, DIM_, DIM_, DIM_, DIM_, DIM_, 0, 0, 0, 1.f, 1);
}

// Round 5
// 924.479 us; speedup vs baseline: 1.4491x; 1.4491x over previous
//
#include <hip/hip_runtime.h>
#include <math.h>

#define B_    2
#define S_    2048
#define M_TOT 4096
#define DIM_  2048
#define NH_   16
#define QL_   1536
#define KVL_  512
#define QKN_  128
#define QKR_  64
#define VH_   128
#define QKH_  192
#define QSTR  3072      // NH_*QKH_
#define QP_STR 584      // padded LDS row stride for resident Q (576+8)

typedef short s16x8 __attribute__((ext_vector_type(8)));
typedef float f32x4 __attribute__((ext_vector_type(4)));
typedef unsigned short u16;
#define AS1 __attribute__((address_space(1)))
#define AS3 __attribute__((address_space(3)))

__device__ inline u16 f2bf(float f) {
    unsigned u = __float_as_uint(f);
    unsigned r = u + 0x7FFFu + ((u >> 16) & 1u);   // round-to-nearest-even
    return (u16)(r >> 16);
}
__device__ inline float bf2f(u16 h) { return __uint_as_float(((unsigned)h) << 16); }

__device__ __forceinline__ void ld_lds16(const u16* g, u16* l) {
    __builtin_amdgcn_global_load_lds((const AS1 unsigned*)g, (AS3 unsigned*)l, 16, 0, 0);
}
// Counted-vmcnt barriers (T3/T4): NEVER drain vmcnt(0) in the main loop.
// Each chunk = 2 global_load_lds per thread; depth-3 ring -> steady state has
// 3 chunks (6 ops) in flight after issue; vmcnt(4) retires the oldest chunk.
// lgkmcnt(0) before every barrier publishes ds_writes AND guarantees all
// waves' ds_reads of the to-be-overwritten ring slot have completed.
#define BARW4 do { asm volatile("s_waitcnt vmcnt(4) lgkmcnt(0)" ::: "memory"); __builtin_amdgcn_s_barrier(); } while (0)
#define BARW2 do { asm volatile("s_waitcnt vmcnt(2) lgkmcnt(0)" ::: "memory"); __builtin_amdgcn_s_barrier(); } while (0)
#define BARW0 do { asm volatile("s_waitcnt vmcnt(0) lgkmcnt(0)" ::: "memory"); __builtin_amdgcn_s_barrier(); } while (0)
#define BARLG do { asm volatile("s_waitcnt lgkmcnt(0)" ::: "memory"); __builtin_amdgcn_s_barrier(); } while (0)

// ---------------------------------------------------------------------------
// m97-pattern bf16 MFMA GEMM (known good since round 2).
// ---------------------------------------------------------------------------
__global__ __launch_bounds__(256)
void gemm_bf16(const u16* __restrict__ A, const u16* __restrict__ Bm,
               const float* __restrict__ bias, void* __restrict__ Cv,
               int M, int N, int K, int ldA, int ldB, int ldC,
               long long sAz, long long sBz, long long sCz,
               float alpha, int outF32)
{
    __shared__ u16 As[128 * 32];
    __shared__ u16 Bs[128 * 32];
    const int tid = threadIdx.x;
    const int w = tid >> 6, l = tid & 63;
    const int m0 = blockIdx.y * 128, n0 = blockIdx.x * 128;
    const int z = blockIdx.z;
    const u16* Az = A + (size_t)z * sAz;
    const u16* Bz = Bm + (size_t)z * sBz;

    const int rin = l >> 2;
    const int cel = (l & 3) * 8;
    const int lane15 = l & 15, quad = l >> 4;
    const int wm = w & 1, wn = w >> 1;

    f32x4 acc[4][4] = {};

    for (int k0 = 0; k0 < K; k0 += 32) {
        __syncthreads();
        #pragma unroll
        for (int c = 0; c < 2; ++c) {
            const int chunk = w * 2 + c;
            const int rowA = m0 + chunk * 16 + rin;
            const u16* ga = Az + (size_t)rowA * ldA + k0 + cel;
            u16* la = &As[chunk * 512 + rin * 32 + cel];
            __builtin_amdgcn_global_load_lds((const AS1 unsigned*)ga, (AS3 unsigned*)la, 16, 0, 0);
            int rowB = n0 + chunk * 16 + rin;
            if (rowB > N - 1) rowB = N - 1;
            const u16* gb = Bz + (size_t)rowB * ldB + k0 + cel;
            u16* lb = &Bs[chunk * 512 + rin * 32 + cel];
            __builtin_amdgcn_global_load_lds((const AS1 unsigned*)gb, (AS3 unsigned*)lb, 16, 0, 0);
        }
        __syncthreads();
        s16x8 af[4], bf[4];
        #pragma unroll
        for (int i = 0; i < 4; ++i)
            af[i] = *(const s16x8*)&As[(wm * 64 + i * 16 + lane15) * 32 + quad * 8];
        #pragma unroll
        for (int i = 0; i < 4; ++i)
            bf[i] = *(const s16x8*)&Bs[(wn * 64 + i * 16 + lane15) * 32 + quad * 8];
        #pragma unroll
        for (int mi = 0; mi < 4; ++mi)
            #pragma unroll
            for (int ni = 0; ni < 4; ++ni)
                acc[mi][ni] = __builtin_amdgcn_mfma_f32_16x16x32_bf16(af[mi], bf[ni], acc[mi][ni], 0, 0, 0);
    }

    const int cmb = m0 + wm * 64, cnb = n0 + wn * 64;
    if (outF32) {
        float* C = (float*)Cv + (size_t)z * sCz;
        #pragma unroll
        for (int mi = 0; mi < 4; ++mi)
            #pragma unroll
            for (int ni = 0; ni < 4; ++ni) {
                const int nn = cnb + ni * 16 + lane15;
                if (nn < N) {
                    const float bv = bias ? bias[nn] : 0.f;
                    #pragma unroll
                    for (int r = 0; r < 4; ++r) {
                        const int mm = cmb + mi * 16 + quad * 4 + r;
                        C[(size_t)mm * ldC + nn] = acc[mi][ni][r] * alpha + bv;
                    }
                }
            }
    } else {
        u16* C = (u16*)Cv + (size_t)z * sCz;
        #pragma unroll
        for (int mi = 0; mi < 4; ++mi)
            #pragma unroll
            for (int ni = 0; ni < 4; ++ni) {
                const int nn = cnb + ni * 16 + lane15;
                if (nn < N) {
                    const float bv = bias ? bias[nn] : 0.f;
                    #pragma unroll
                    for (int r = 0; r < 4; ++r) {
                        const int mm = cmb + mi * 16 + quad * 4 + r;
                        C[(size_t)mm * ldC + nn] = f2bf(acc[mi][ni][r] * alpha + bv);
                    }
                }
            }
    }
}

// ---------------------------------------------------------------------------
// Flash v7 = v5 geometry (512 thr / 8 waves / 64 q-rows, 1 block/CU) with a
// depth-3 counted-vmcnt pipeline (T3+T4). v5 drained vmcnt(0) every phase,
// exposing ~300-600 cyc DMA latency x 17 phases/tile (MfmaUtil 16%). v6's
// 2-block occupancy route FAILED (allocator gave 1 block/CU at 80KB LDS;
// 886us). v7 instead hides latency within one block:
//   - sKV = 4 x 16KB ring. 17 chunks/tile: K chunks j=0..8 (64 dims x 128
//     keys), V chunks 9..16 ((tc,hf): 256 c-rows x 32 t). buf(c) = (t+c)&3.
//   - slot s: issue chunk c(s)+3 -> compute chunk c(s) -> vmcnt(4) barrier.
//     Loads stay 3 slots in flight; never drained to 0 mid-loop.
//   - slot-exact wait table (verified): slots 0-5 W4; 6 (no issue, softmax
//     consumption gap) W2; 7,8 W2; 9 (softmax-only, issues c11) lgkm-only;
//     PV slots W4; last-tile tail W4/W2/W0. Ring overwrite always >=1
//     barrier after last read (G vs G-4 separation).
// Softmax, XOR source-permute swizzle (sx8/qx8), XCD decode: v5 verbatim.
// LDS: 74752(Q) + 65536(4x16KB ring) + 17408(P) + 2560(misc) = 160256 B
// (byte-identical to v5's known-resident footprint).
// ---------------------------------------------------------------------------
__global__ __launch_bounds__(512)
void mla_flash(u16* __restrict__ Qp, const u16* __restrict__ Kcat,
               const u16* __restrict__ KVT)
{
    __shared__ u16 sQ[64 * QP_STR];          // 74752 B
    __shared__ u16 sKV[4 * 8192];            // 65536 B: 4 ring bufs x 16KB
    __shared__ u16 sP[64 * 136];             // 17408 B
    __shared__ float sRm[64 * 4];            // per-row max partials (4 k-slices)
    __shared__ float sRs[64 * 4];            // per-row sum partials
    __shared__ float sM[64], sL[64];

    const int tid = threadIdx.x;
    const int w = tid >> 6, l = tid & 63;
    const int lane15 = l & 15, quad = l >> 4;
    const int wq = w & 1;                    // q-half (rows wq*32 ..)
    const int wk = w >> 1;                   // score k-slice / PV c-sub-slice

    // --- XCD-aware decode (bijective over 1024): b pinned per XCD half ---
    const int flat = blockIdx.x;
    const int xcd  = flat & 7;
    const int slot = flat >> 3;              // 0..127
    const int b    = xcd >> 2;
    const int h    = (xcd & 3) * 4 + (slot & 3);
    const int qt   = 31 - (slot >> 2);       // heavy tiles first
    const int qs   = qt * 64;

    u16* Qrow = Qp + ((size_t)h * M_TOT + b * S_ + qs) * 576;
    const float scale = 0.07216878364870323f;  // 1/sqrt(192)
    const u16* Kb = Kcat + (size_t)b * S_ * 576;
    const u16* Vb = KVT + (size_t)b * 512 * S_;

    const int seg8 = (tid & 3) * 8;          // linear LDS dest segment
    const int sx8  = (((tid & 3) ^ ((tid >> 3) & 3)) * 8);   // permuted SRC segment
    const int qx8  = ((quad ^ ((lane15 >> 1) & 3)) * 8);     // permuted READ segment
    const int ktiles = (qs + 64 + 127) >> 7;

    // K chunk j (dims j*64..+64) -> ring buf: [kk 2][key 128][32], 2 loads/thr
    auto issueK = [&](int kt, int j, int buf) {
        const int key = tid >> 2;
        const u16* g = Kb + (size_t)(kt + key) * 576 + j * 64 + sx8;
        u16* d = &sKV[(buf << 13) + key * 32 + seg8];
        ld_lds16(g, d);                       // kk = 0
        ld_lds16(g + 32, d + 4096);           // kk = 1 (dims +32)
    };
    // V chunk (tc, hf): 256 c-rows x 32 t -> ring buf: [rl 256][32], 2 loads/thr
    auto issueV = [&](int kt, int tc, int hf, int buf) {
        const int rl = tid >> 2;
        const u16* g = Vb + (size_t)(hf * 256 + rl) * S_ + kt + tc * 32 + sx8;
        u16* d = &sKV[(buf << 13) + rl * 32 + seg8];
        ld_lds16(g, d);                       // rows rl
        ld_lds16(g + (size_t)128 * S_, d + 4096);   // rows rl+128
    };
    auto scoreC = [&](int j, int buf, f32x4 (&Sacc)[2][2]) {
        const u16* base = &sKV[buf << 13];
        __builtin_amdgcn_s_setprio(1);
        #pragma unroll
        for (int kk = 0; kk < 2; ++kk) {
            s16x8 af[2], bf[2];
            #pragma unroll
            for (int mi = 0; mi < 2; ++mi)
                af[mi] = *(const s16x8*)&sQ[(wq * 32 + mi * 16 + lane15) * QP_STR + j * 64 + kk * 32 + quad * 8];
            #pragma unroll
            for (int ni = 0; ni < 2; ++ni)
                bf[ni] = *(const s16x8*)&base[kk * 4096 + (wk * 32 + ni * 16 + lane15) * 32 + qx8];
            #pragma unroll
            for (int mi = 0; mi < 2; ++mi)
                #pragma unroll
                for (int ni = 0; ni < 2; ++ni)
                    Sacc[mi][ni] = __builtin_amdgcn_mfma_f32_16x16x32_bf16(af[mi], bf[ni], Sacc[mi][ni], 0, 0, 0);
        }
        __builtin_amdgcn_s_setprio(0);
    };

    // ---- prologue: issue K chunks 0,1,2 first, hide under Q fill ----
    issueK(0, 0, 0);
    issueK(0, 1, 1);
    issueK(0, 2, 2);
    {
        const int r = tid >> 3, c0 = (tid & 7) * 8;   // 64 rows x 576
        #pragma unroll
        for (int jj = 0; jj < 9; ++jj) {
            const int c = c0 + jj * 64;
            *(s16x8*)&sQ[r * QP_STR + c] = *(const s16x8*)&Qrow[(size_t)r * 576 + c];
        }
    }
    if (tid < 64) { sM[tid] = -1e30f; sL[tid] = 0.f; }
    BARW4;                                   // c0 retired (Q loads are newer)

    f32x4 Oacc[2][8] = {};   // rows wq*32+mi*16+...; cols hf*256+wk*64+ci*16 -> Oacc[mi][hf*4+ci]

    for (int t = 0; t < ktiles; ++t) {
        const int kt = t << 7;
        const int tb = t & 3;                // buf(chunk c) = (tb + c) & 3
        const bool hn = (t + 1 < ktiles);
        f32x4 Sacc[2][2] = {};

        // ---- slots 0..5: issue K(s+3), compute K(s), W4 ----
        #pragma unroll
        for (int s = 0; s < 6; ++s) {
            issueK(kt, s + 3, (tb + s + 3) & 3);
            scoreC(s, (tb + s) & 3, Sacc);
            BARW4;
        }
        // ---- slot 6: consumption gap (softmax slot shifts V) -> no issue ----
        scoreC(6, (tb + 6) & 3, Sacc);
        BARW2;
        // ---- slot 7: issue c9 = V(0,0) ----
        issueV(kt, 0, 0, (tb + 9) & 3);
        scoreC(7, (tb + 7) & 3, Sacc);
        BARW2;
        // ---- slot 8: issue c10 = V(0,1); compute K(8) + softmax part 1 ----
        issueV(kt, 0, 1, (tb + 10) & 3);
        scoreC(8, (tb + 8) & 3, Sacc);
        #pragma unroll
        for (int mi = 0; mi < 2; ++mi)
            #pragma unroll
            for (int r = 0; r < 4; ++r) {
                const int rowl = wq * 32 + mi * 16 + quad * 4 + r;
                const int rowg = qs + rowl;
                float mx = -1e30f;
                #pragma unroll
                for (int ni = 0; ni < 2; ++ni) {
                    const int colg = kt + wk * 32 + ni * 16 + lane15;
                    float v = Sacc[mi][ni][r] * scale;
                    v = (colg <= rowg) ? v : -1e30f;
                    Sacc[mi][ni][r] = v;
                    mx = fmaxf(mx, v);
                }
                #pragma unroll
                for (int sh = 1; sh < 16; sh <<= 1) mx = fmaxf(mx, __shfl_xor(mx, sh));
                if (lane15 == 0) sRm[rowl * 4 + wk] = mx;
            }
        BARW2;                               // sRm visible; c9 retired

        // ---- slot 9 (softmax part 2): issue c11 = V(1,0); no vm wait ----
        issueV(kt, 1, 0, (tb + 11) & 3);
        float mn_[2][4], al_[2][4];
        #pragma unroll
        for (int mi = 0; mi < 2; ++mi)
            #pragma unroll
            for (int r = 0; r < 4; ++r) {
                const int rowl = wq * 32 + mi * 16 + quad * 4 + r;
                const f32x4 pm = *(const f32x4*)&sRm[rowl * 4];   // broadcast b128
                const float m_old = sM[rowl];
                const float mn = fmaxf(fmaxf(fmaxf(pm[0], pm[1]), fmaxf(pm[2], pm[3])), m_old);
                const float al = __expf(m_old - mn);
                mn_[mi][r] = mn; al_[mi][r] = al;
                float sum = 0.f;
                #pragma unroll
                for (int ni = 0; ni < 2; ++ni) {
                    const float p = __expf(Sacc[mi][ni][r] - mn);
                    sP[rowl * 136 + wk * 32 + ni * 16 + lane15] = f2bf(p);
                    sum += p;
                }
                #pragma unroll
                for (int ci = 0; ci < 8; ++ci) Oacc[mi][ci][r] *= al;
                #pragma unroll
                for (int sh = 1; sh < 16; sh <<= 1) sum += __shfl_xor(sum, sh);
                if (lane15 == 0) sRs[rowl * 4 + wk] = sum;
            }
        BARLG;                               // sP + sRs visible; c9/c10 already retired

        // ---- part 3: designated lanes update per-row m/l (consumers >=1 barrier away) ----
        if (wk == 0 && lane15 == 0) {
            #pragma unroll
            for (int mi = 0; mi < 2; ++mi)
                #pragma unroll
                for (int r = 0; r < 4; ++r) {
                    const int rowl = wq * 32 + mi * 16 + quad * 4 + r;
                    const f32x4 ps = *(const f32x4*)&sRs[rowl * 4];
                    sL[rowl] = sL[rowl] * al_[mi][r] + (ps[0] + ps[1] + ps[2] + ps[3]);
                    sM[rowl] = mn_[mi][r];
                }
        }

        // ---- PV slots k=0..7: compute chunk 9+k, issue chunk 12+k ----
        #pragma unroll
        for (int k = 0; k < 8; ++k) {
            const int cis = 12 + k;          // chunk to issue
            if (cis <= 16)      issueV(kt, (cis - 9) >> 1, (cis - 9) & 1, (tb + cis) & 3);
            else if (hn)        issueK(kt + 128, cis - 17, (tb + 1 + (cis - 17)) & 3);
            {
                const int tc = k >> 1, hf = k & 1;
                const u16* base = &sKV[(((tb + 9 + k) & 3)) << 13];
                s16x8 pf[2], vf[4];
                #pragma unroll
                for (int mi = 0; mi < 2; ++mi)
                    pf[mi] = *(const s16x8*)&sP[(wq * 32 + mi * 16 + lane15) * 136 + tc * 32 + quad * 8];
                #pragma unroll
                for (int ci = 0; ci < 4; ++ci) {
                    const int rl = wk * 64 + ci * 16 + lane15;   // 0..255 within half
                    vf[ci] = *(const s16x8*)&base[rl * 32 + qx8];
                }
                __builtin_amdgcn_s_setprio(1);
                #pragma unroll
                for (int mi = 0; mi < 2; ++mi)
                    #pragma unroll
                    for (int ci = 0; ci < 4; ++ci)
                        Oacc[mi][hf * 4 + ci] = __builtin_amdgcn_mfma_f32_16x16x32_bf16(pf[mi], vf[ci], Oacc[mi][hf * 4 + ci], 0, 0, 0);
                __builtin_amdgcn_s_setprio(0);
            }
            if (k < 5 || hn) { BARW4; }
            else if (k == 5) { BARW2; }      // last tile, c0'/c1'/c2' not issued
            else if (k == 6) { BARW0; }
            // k == 7 on last tile: nothing outstanding; fall through to epilogue
        }
    }

    // ---- epilogue: O/l -> bf16, overwrite Qpack[..., 0:512] ----
    #pragma unroll
    for (int mi = 0; mi < 2; ++mi)
        #pragma unroll
        for (int r = 0; r < 4; ++r) {
            const int rowl = wq * 32 + mi * 16 + quad * 4 + r;
            const float inv = 1.f / sL[rowl];
            #pragma unroll
            for (int hf = 0; hf < 2; ++hf)
                #pragma unroll
                for (int ci = 0; ci < 4; ++ci)
                    Qrow[(size_t)rowl * 576 + hf * 256 + wk * 64 + ci * 16 + lane15] =
                        f2bf(Oacc[mi][hf * 4 + ci][r] * inv);
        }
}

// ---------------------------------------------------------------------------
__global__ __launch_bounds__(256)
void cast_f32_bf16(const float* __restrict__ src, u16* __restrict__ dst, int n)
{
    for (int i = blockIdx.x * 256 + threadIdx.x; i < n; i += gridDim.x * 256)
        dst[i] = f2bf(src[i]);
}

__global__ __launch_bounds__(256)
void prep_wbnT(const float* __restrict__ wkvb, u16* __restrict__ dst)
{
    int i = blockIdx.x * 256 + threadIdx.x;
    int h = i >> 16, rem = i & 65535, c = rem >> 7, d = rem & 127;
    dst[i] = f2bf(wkvb[(size_t)(h * 256 + d) * 512 + c]);
}

__global__ __launch_bounds__(256)
void prep_wbv(const float* __restrict__ wkvb, u16* __restrict__ dst)
{
    int i = blockIdx.x * 256 + threadIdx.x;
    int h = i >> 16, rem = i & 65535;
    dst[i] = f2bf(wkvb[(size_t)h * 131072 + 65536 + rem]);
}

__global__ __launch_bounds__(256)
void rmsnorm_bf16(u16* __restrict__ X, const float* __restrict__ w, int D)
{
    const int m = blockIdx.x;
    u16* x = X + (size_t)m * D;
    float ss = 0.f;
    for (int k = threadIdx.x; k < D; k += 256) { float v = bf2f(x[k]); ss += v * v; }
    __shared__ float red[256];
    red[threadIdx.x] = ss; __syncthreads();
    for (int s = 128; s > 0; s >>= 1) {
        if (threadIdx.x < s) red[threadIdx.x] += red[threadIdx.x + s];
        __syncthreads();
    }
    const float sc = rsqrtf(red[0] / (float)D + 1e-6f);
    for (int k = threadIdx.x; k < D; k += 256) x[k] = f2bf(bf2f(x[k]) * sc * w[k]);
}

// q (bf16, rows QSTR) -> rotate q_pe, write to Qpack[h][m][512:576]
__global__ __launch_bounds__(256)
void rope_q(const u16* __restrict__ q, const float* __restrict__ freqs, u16* __restrict__ Qp)
{
    const int idx = blockIdx.x * 256 + threadIdx.x;
    const int i = idx & 31, h = (idx >> 5) & 15, m = idx >> 9;
    const int s = m & (S_ - 1);
    const float c = freqs[(s * 32 + i) * 2], sn = freqs[(s * 32 + i) * 2 + 1];
    const u16* src = q + (size_t)m * QSTR + h * QKH_ + QKN_ + 2 * i;
    const float x0 = bf2f(src[0]), x1 = bf2f(src[1]);
    u16* dst = Qp + ((size_t)h * M_TOT + m) * 576 + 512 + 2 * i;
    dst[0] = f2bf(x0 * c - x1 * sn);
    dst[1] = f2bf(x1 * c + x0 * sn);
}

__global__ __launch_bounds__(256)
void kv_norm_rope(const u16* __restrict__ kva, const float* __restrict__ w,
                  const float* __restrict__ freqs, u16* __restrict__ Kcat)
{
    const int m = blockIdx.x, s = m & (S_ - 1);
    const u16* x = kva + (size_t)m * 576;
    float ss = 0.f;
    for (int k = threadIdx.x; k < 512; k += 256) { float v = bf2f(x[k]); ss += v * v; }
    __shared__ float red[256];
    red[threadIdx.x] = ss; __syncthreads();
    for (int st = 128; st > 0; st >>= 1) {
        if (threadIdx.x < st) red[threadIdx.x] += red[threadIdx.x + st];
        __syncthreads();
    }
    const float sc = rsqrtf(red[0] / 512.f + 1e-6f);
    for (int k = threadIdx.x; k < 512; k += 256)
        Kcat[(size_t)m * 576 + k] = f2bf(bf2f(x[k]) * sc * w[k]);
    if (threadIdx.x < 32) {
        const int i = threadIdx.x;
        const float c = freqs[(s * 32 + i) * 2], sn = freqs[(s * 32 + i) * 2 + 1];
        const float x0 = bf2f(x[512 + 2 * i]), x1 = bf2f(x[512 + 2 * i + 1]);
        Kcat[(size_t)m * 576 + 512 + 2 * i]     = f2bf(x0 * c - x1 * sn);
        Kcat[(size_t)m * 576 + 512 + 2 * i + 1] = f2bf(x1 * c + x0 * sn);
    }
}

__global__ __launch_bounds__(256)
void transpose_kv(const u16* __restrict__ Kcat, u16* __restrict__ KVT)
{
    __shared__ u16 t[64][65];
    const int s0 = blockIdx.x * 64, c0 = blockIdx.y * 64, b = blockIdx.z;
    #pragma unroll
    for (int i = 0; i < 16; ++i) {
        int id = i * 256 + threadIdx.x, r = id >> 6, c = id & 63;
        t[r][c] = Kcat[(size_t)(b * S_ + s0 + r) * 576 + c0 + c];
    }
    __syncthreads();
    #pragma unroll
    for (int i = 0; i < 16; ++i) {
        int id = i * 256 + threadIdx.x, r = id >> 6, c = id & 63;
        KVT[(size_t)(b * 512 + c0 + r) * S_ + s0 + c] = t[c][r];
    }
}

// ---------------------------------------------------------------------------
extern "C" void kernel_launch(void* const* d_in, const int* in_sizes, int n_in,
                              void* d_out, int out_size, void* d_ws, size_t ws_size,
                              hipStream_t stream)
{
    (void)in_sizes; (void)n_in; (void)out_size; (void)ws_size;
    const float* x         = (const float*)d_in[0];
    const float* freqs     = (const float*)d_in[1];
    const float* wq_a_w    = (const float*)d_in[4];
    const float* wq_a_b    = (const float*)d_in[5];
    const float* q_norm_w  = (const float*)d_in[6];
    const float* wq_b_w    = (const float*)d_in[7];
    const float* wq_b_b    = (const float*)d_in[8];
    const float* wkv_a_w   = (const float*)d_in[9];
    const float* wkv_a_b   = (const float*)d_in[10];
    const float* kv_norm_w = (const float*)d_in[11];
    const float* wkv_b_w   = (const float*)d_in[12];
    const float* wo_w      = (const float*)d_in[13];
    const float* wo_b      = (const float*)d_in[14];
    float* out = (float*)d_out;

    char* W = (char*)d_ws;
    u16* x_bf  = (u16*)(W + 0);
    u16* wqa   = (u16*)(W + 16777216);
    u16* wqb   = (u16*)(W + 23068672);
    u16* wkva  = (u16*)(W + 32505856);
    u16* wobf  = (u16*)(W + 34865152);
    u16* wbnT  = (u16*)(W + 43253760);
    u16* wbv   = (u16*)(W + 45350912);
    u16* q_a   = (u16*)(W + 47448064);
    u16* q     = (u16*)(W + 60030976);
    u16* kv_a  = (u16*)(W + 85196800);
    u16* Kcat  = (u16*)(W + 89915392);
    u16* KVT   = (u16*)(W + 94633984);
    u16* Qp    = (u16*)(W + 98828288);   // Qpack[h][4096][576]: q_abs|q_pe -> attn out
    u16* outh  = (u16*)(W + 174325760);

    const dim3 blk(256);

    // --- dtype prep ---
    cast_f32_bf16<<<2048, blk, 0, stream>>>(x, x_bf, M_TOT * DIM_);
    cast_f32_bf16<<<2048, blk, 0, stream>>>(wq_a_w, wqa, QL_ * DIM_);
    cast_f32_bf16<<<2048, blk, 0, stream>>>(wq_b_w, wqb, QSTR * QL_);
    cast_f32_bf16<<<2048, blk, 0, stream>>>(wkv_a_w, wkva, 576 * DIM_);
    cast_f32_bf16<<<2048, blk, 0, stream>>>(wo_w, wobf, DIM_ * DIM_);
    prep_wbnT<<<4096, blk, 0, stream>>>(wkv_b_w, wbnT);
    prep_wbv<<<4096, blk, 0, stream>>>(wkv_b_w, wbv);

    // --- q path ---
    gemm_bf16<<<dim3(12, 32, 1), blk, 0, stream>>>(x_bf, wqa, wq_a_b, q_a,
        M_TOT, QL_, DIM_, DIM_, DIM_, QL_, 0, 0, 0, 1.f, 0);
    rmsnorm_bf16<<<M_TOT, blk, 0, stream>>>(q_a, q_norm_w, QL_);
    gemm_bf16<<<dim3(24, 32, 1), blk, 0, stream>>>(q_a, wqb, wq_b_b, q,
        M_TOT, QSTR, QL_, QL_, QL_, QSTR, 0, 0, 0, 1.f, 0);
    rope_q<<<(M_TOT * NH_ * 32) / 256, blk, 0, stream>>>(q, freqs, Qp);

    // --- kv path ---
    gemm_bf16<<<dim3(5, 32, 1), blk, 0, stream>>>(x_bf, wkva, wkv_a_b, kv_a,
        M_TOT, 576, DIM_, DIM_, DIM_, 576, 0, 0, 0, 1.f, 0);
    kv_norm_rope<<<M_TOT, blk, 0, stream>>>(kv_a, kv_norm_w, freqs, Kcat);
    transpose_kv<<<dim3(32, 8, 2), blk, 0, stream>>>(Kcat, KVT);

    // --- q absorb: Qpack[h][m][0:512] = q_nope @ wkv_b[h,:128,:] ---
    gemm_bf16<<<dim3(4, 32, 16), blk, 0, stream>>>(q, wbnT, nullptr, Qp,
        M_TOT, 512, 128, QSTR, 128, 576, QKH_, 65536, (long long)M_TOT * 576, 1.f, 0);

    // --- fused flash attention v7 (depth-3 counted-vmcnt pipeline) ---
    mla_flash<<<dim3(1024, 1, 1), dim3(512), 0, stream>>>(Qp, Kcat, KVT);

    // --- V projection: outh[m][h*128+d] = O[h][m][:] . wbv[h][d][:] ---
    gemm_bf16<<<dim3(1, 32, 16), blk, 0, stream>>>(Qp, wbv, nullptr, outh,
        M_TOT, VH_, 512, 576, 512, DIM_, (long long)M_TOT * 576, 65536, VH_, 1.f, 0);

    // --- output projection (fp32 out) ---
    gemm_bf16<<<dim3(16, 32, 1), blk, 0, stream>>>(outh, wobf, wo_b, out,
        M_TOT, DIM_, DIM_, DIM_, DIM_, DIM_, 0, 0, 0, 1.f, 1);
}